// Round 8
// baseline (612.505 us; speedup 1.0000x reference)
//
#include <hip/hip_runtime.h>
#include <cstdint>

#define NB  8
#define C2  256
#define C3  512
#define NCH 128
#define NN2 4096
#define NN3 4096

using f4 = float4;
typedef float f32x16 __attribute__((ext_vector_type(16)));
typedef __bf16 bf16x8 __attribute__((ext_vector_type(8)));

union FragU {
    uint4    q;
    uint32_t u[4];
    bf16x8   v;
};

__device__ __forceinline__ unsigned short f2bf(float f) {
    uint32_t u = __float_as_uint(f);
    u += 0x7fffu + ((u >> 16) & 1u);
    return (unsigned short)(u >> 16);
}
__device__ __forceinline__ float bf2f(unsigned short h) {
    return __uint_as_float(((uint32_t)h) << 16);
}
__device__ __forceinline__ uint32_t pkbf(float lo, float hi) {
    union { __bf16 h[2]; uint32_t u; } t;
    t.h[0] = (__bf16)lo;
    t.h[1] = (__bf16)hi;
    return t.u;
}
__device__ __forceinline__ void fma4(float* acc, float a, const f4 w) {
    acc[0] = fmaf(a, w.x, acc[0]);
    acc[1] = fmaf(a, w.y, acc[1]);
    acc[2] = fmaf(a, w.z, acc[2]);
    acc[3] = fmaf(a, w.w, acc[3]);
}

// ---------------------------------------------------------------------------
// Kernel 0a: repack Wps [co][ci][3][3] f32 -> Wb [tap][co][ci] bf16
// ---------------------------------------------------------------------------
__global__ __launch_bounds__(256) void wprep(const float* __restrict__ Wps,
                                             unsigned short* __restrict__ Wb) {
    int idx = blockIdx.x * 256 + threadIdx.x;       // < 589824
    int t = idx >> 16;
    int r = idx & 65535;
    int co = r >> 8, ci = r & 255;
    Wb[idx] = f2bf(Wps[((size_t)(co * 256 + ci)) * 9 + t]);
}

// ---------------------------------------------------------------------------
// Kernel 0b: convert Wq/Wk/Wv f32 -> bf16 (same row-major [c][k] layout)
// ---------------------------------------------------------------------------
__global__ __launch_bounds__(256) void wprep2(const float* __restrict__ Wq,
                                              const float* __restrict__ Wk,
                                              const float* __restrict__ Wv,
                                              unsigned short* __restrict__ Wqb,
                                              unsigned short* __restrict__ Wkb,
                                              unsigned short* __restrict__ Wvb) {
    int idx = blockIdx.x * 256 + threadIdx.x;       // < 163840
    if (idx < 32768)        Wqb[idx]          = f2bf(Wq[idx]);
    else if (idx < 98304)   Wkb[idx - 32768]  = f2bf(Wk[idx - 32768]);
    else                    Wvb[idx - 98304]  = f2bf(Wv[idx - 98304]);
}

// ---------------------------------------------------------------------------
// Kernel 1: Q projection via bf16 MFMA. Q[b][n][c] = Wq·f2d + bq.
// Block: 256 thr / 4 waves; n-tile 128 (32/wave); K = 256 in 8 chunks of 32.
// f32->bf16 transpose staging into Xs[n][40] (pad 40 -> 2-way-free writes).
// Q via mfma(A=Wq, B=X): D col=n(i31), row=c -> c-quad ushort4 stores.
// ---------------------------------------------------------------------------
__global__ __launch_bounds__(256) void proj_q(const float* __restrict__ f2d,
                                              const unsigned short* __restrict__ Wqb,
                                              const float* __restrict__ bq,
                                              unsigned short* __restrict__ Q) {
    __shared__ __align__(16) unsigned short Xs[2][128 * 40];
    const int tid = threadIdx.x;
    const int b  = blockIdx.x >> 5;
    const int n0 = (blockIdx.x & 31) << 7;
    const int wn = tid >> 6;
    const int lane = tid & 63;
    const int i31 = lane & 31;
    const int h   = lane >> 5;
    const int kp = tid >> 4;       // 0..15 (k-pair)
    const int nc = tid & 15;       // n strided by 16

    f32x16 aQ[4];
#pragma unroll
    for (int cf = 0; cf < 4; cf++)
#pragma unroll
        for (int r = 0; r < 16; r++) aQ[cf][r] = 0.f;

    float xlo[8], xhi[8];
    auto LOADC = [&](int k0) {
        const float* r0 = f2d + ((size_t)b * C2 + k0 + 2 * kp) * NN2 + n0 + nc;
        const float* r1 = r0 + NN2;
#pragma unroll
        for (int i = 0; i < 8; i++) { xlo[i] = r0[16 * i]; xhi[i] = r1[16 * i]; }
    };
    auto WRITEC = [&](int bi) {
        unsigned short* X = Xs[bi];
#pragma unroll
        for (int i = 0; i < 8; i++)
            *(uint32_t*)&X[(nc + 16 * i) * 40 + 2 * kp] = pkbf(xlo[i], xhi[i]);
    };

    LOADC(0); WRITEC(0); __syncthreads();
    int cur = 0;
    for (int c = 0; c < 8; c++) {
        if (c + 1 < 8) LOADC((c + 1) * 32);
        const int k0 = c * 32;
        FragU xf[2];
        xf[0].q = *(const uint4*)&Xs[cur][(wn * 32 + i31) * 40 + h * 8];
        xf[1].q = *(const uint4*)&Xs[cur][(wn * 32 + i31) * 40 + 16 + h * 8];
#pragma unroll
        for (int ks = 0; ks < 2; ks++) {
            const int ko = k0 + ks * 16 + h * 8;
#pragma unroll
            for (int cf = 0; cf < 4; cf++) {
                FragU wq;
                wq.q = *(const uint4*)&Wqb[(size_t)(cf * 32 + i31) * 256 + ko];
                aQ[cf] = __builtin_amdgcn_mfma_f32_32x32x16_bf16(wq.v, xf[ks].v, aQ[cf], 0, 0, 0);
            }
        }
        if (c + 1 < 8) WRITEC(cur ^ 1);
        __syncthreads();
        cur ^= 1;
    }
    const int nQ = n0 + wn * 32 + i31;
    unsigned short* Qrow = Q + ((size_t)b * NN2 + nQ) * NCH;
#pragma unroll
    for (int cf = 0; cf < 4; cf++)
#pragma unroll
        for (int tq = 0; tq < 4; tq++) {
            int c0 = cf * 32 + 8 * tq + 4 * h;
            f4 bb = *(const f4*)(bq + c0);
            ushort4 s;
            s.x = f2bf(aQ[cf][4 * tq + 0] + bb.x);
            s.y = f2bf(aQ[cf][4 * tq + 1] + bb.y);
            s.z = f2bf(aQ[cf][4 * tq + 2] + bb.z);
            s.w = f2bf(aQ[cf][4 * tq + 3] + bb.w);
            *(ushort4*)(Qrow + c0) = s;
        }
}

// ---------------------------------------------------------------------------
// Kernel 2: K/V projections via bf16 MFMA (share the staged X tile).
// K[b][n][c] via mfma(A=Wk,B=X); Vt[b][c][n] via mfma(A=X,B=Wv) (n-quad
// stores give the transposed layout for free). K-dim 512 in 16 chunks.
// ---------------------------------------------------------------------------
__global__ __launch_bounds__(256) void proj_kv(const float* __restrict__ f3d,
                                               const unsigned short* __restrict__ Wkb,
                                               const float* __restrict__ bk,
                                               const unsigned short* __restrict__ Wvb,
                                               const float* __restrict__ bv,
                                               unsigned short* __restrict__ K,
                                               unsigned short* __restrict__ Vt) {
    __shared__ __align__(16) unsigned short Xs[2][128 * 40];
    const int tid = threadIdx.x;
    const int b  = blockIdx.x >> 5;
    const int n0 = (blockIdx.x & 31) << 7;
    const int wn = tid >> 6;
    const int lane = tid & 63;
    const int i31 = lane & 31;
    const int h   = lane >> 5;
    const int kp = tid >> 4;
    const int nc = tid & 15;

    f32x16 aK[4], aV[4];
#pragma unroll
    for (int cf = 0; cf < 4; cf++)
#pragma unroll
        for (int r = 0; r < 16; r++) { aK[cf][r] = 0.f; aV[cf][r] = 0.f; }

    float xlo[8], xhi[8];
    auto LOADC = [&](int k0) {
        const float* r0 = f3d + ((size_t)b * C3 + k0 + 2 * kp) * NN3 + n0 + nc;
        const float* r1 = r0 + NN3;
#pragma unroll
        for (int i = 0; i < 8; i++) { xlo[i] = r0[16 * i]; xhi[i] = r1[16 * i]; }
    };
    auto WRITEC = [&](int bi) {
        unsigned short* X = Xs[bi];
#pragma unroll
        for (int i = 0; i < 8; i++)
            *(uint32_t*)&X[(nc + 16 * i) * 40 + 2 * kp] = pkbf(xlo[i], xhi[i]);
    };

    LOADC(0); WRITEC(0); __syncthreads();
    int cur = 0;
    for (int c = 0; c < 16; c++) {
        if (c + 1 < 16) LOADC((c + 1) * 32);
        const int k0 = c * 32;
        FragU xf[2];
        xf[0].q = *(const uint4*)&Xs[cur][(wn * 32 + i31) * 40 + h * 8];
        xf[1].q = *(const uint4*)&Xs[cur][(wn * 32 + i31) * 40 + 16 + h * 8];
#pragma unroll
        for (int ks = 0; ks < 2; ks++) {
            const int ko = k0 + ks * 16 + h * 8;
#pragma unroll
            for (int cf = 0; cf < 4; cf++) {
                FragU wk, wv;
                wk.q = *(const uint4*)&Wkb[(size_t)(cf * 32 + i31) * 512 + ko];
                wv.q = *(const uint4*)&Wvb[(size_t)(cf * 32 + i31) * 512 + ko];
                aK[cf] = __builtin_amdgcn_mfma_f32_32x32x16_bf16(wk.v, xf[ks].v, aK[cf], 0, 0, 0);
                aV[cf] = __builtin_amdgcn_mfma_f32_32x32x16_bf16(xf[ks].v, wv.v, aV[cf], 0, 0, 0);
            }
        }
        if (c + 1 < 16) WRITEC(cur ^ 1);
        __syncthreads();
        cur ^= 1;
    }
    // K epilogue: lane n fixed, c-quads
    const int nK = n0 + wn * 32 + i31;
    unsigned short* Krow = K + ((size_t)b * NN3 + nK) * NCH;
#pragma unroll
    for (int cf = 0; cf < 4; cf++)
#pragma unroll
        for (int tq = 0; tq < 4; tq++) {
            int c0 = cf * 32 + 8 * tq + 4 * h;
            f4 bb = *(const f4*)(bk + c0);
            ushort4 s;
            s.x = f2bf(aK[cf][4 * tq + 0] + bb.x);
            s.y = f2bf(aK[cf][4 * tq + 1] + bb.y);
            s.z = f2bf(aK[cf][4 * tq + 2] + bb.z);
            s.w = f2bf(aK[cf][4 * tq + 3] + bb.w);
            *(ushort4*)(Krow + c0) = s;
        }
    // V epilogue: lane c fixed, n-quads -> Vt[b][c][n]
#pragma unroll
    for (int cf = 0; cf < 4; cf++) {
        const int cV = cf * 32 + i31;
        const float bvv = bv[cV];
        unsigned short* Vrow = Vt + ((size_t)b * NCH + cV) * NN3;
#pragma unroll
        for (int tq = 0; tq < 4; tq++) {
            int nq = n0 + wn * 32 + 8 * tq + 4 * h;
            ushort4 s;
            s.x = f2bf(aV[cf][4 * tq + 0] + bvv);
            s.y = f2bf(aV[cf][4 * tq + 1] + bvv);
            s.z = f2bf(aV[cf][4 * tq + 2] + bvv);
            s.w = f2bf(aV[cf][4 * tq + 3] + bvv);
            *(ushort4*)(Vrow + nq) = s;
        }
    }
}

// ---------------------------------------------------------------------------
// Kernel 3: flash attention, bf16 MFMA, in-block KV-split x2.
// 256 thr = 4 waves: pair {0,1} keys [0,2048), pair {2,3} keys [2048,4096);
// each pair owns a 32KB double-buffered 32-key tile region. 64 q-rows/block
// (waves w and w+2 share q-rows). LDS merge of (m,l,O) partials at the end.
// s_setprio(1) around MFMA clusters.
// ---------------------------------------------------------------------------
__global__ __launch_bounds__(256) void attn(const unsigned short* __restrict__ Qg,
                                            const unsigned short* __restrict__ Kg,
                                            const unsigned short* __restrict__ Vtg,
                                            unsigned short* __restrict__ AO) {
    __shared__ __align__(16) unsigned short smem[32768];   // 64 KiB
    const int tid = threadIdx.x;
    const int b  = blockIdx.x >> 6;
    const int qc = blockIdx.x & 63;
    const int wid = tid >> 6;
    const int lane = tid & 63;
    const int i31 = lane & 31;
    const int h   = lane >> 5;
    const int p    = wid >> 1;          // key-half
    const int tid2 = tid & 127;         // within pair
    const int q0w  = qc * 64 + (wid & 1) * 32;
    const int kbase = p * 2048;
    unsigned short* Ksp = smem + p * 16384;          // [2][32*128]
    unsigned short* Vsp = smem + p * 16384 + 8192;   // [2][128*32]

    uint4 qf[8];
    const unsigned short* Qrow = Qg + ((size_t)b * NN2 + q0w + i31) * NCH;
#pragma unroll
    for (int dc = 0; dc < 8; dc++) qf[dc] = *(const uint4*)(Qrow + dc * 16 + h * 8);

    f32x16 o[4];
#pragma unroll
    for (int cf = 0; cf < 4; cf++)
#pragma unroll
        for (int r = 0; r < 16; r++) o[cf][r] = 0.f;
    float m_run = -3.0e38f, l_run = 0.f;

    const unsigned short* Kb = Kg  + (size_t)b * NN3 * NCH;
    const unsigned short* Vb = Vtg + (size_t)b * NCH * NN3;

    uint4 kst[4], vst[4];
#pragma unroll
    for (int j = 0; j < 4; j++) {
        int idx = tid2 + 128 * j;
        int key = idx >> 4, g = idx & 15;
        kst[j] = *(const uint4*)(Kb + (size_t)(kbase + key) * NCH + g * 8);
        int c = idx >> 2, gm = idx & 3;
        vst[j] = *(const uint4*)(Vb + (size_t)c * NN3 + kbase + gm * 8);
    }
#pragma unroll
    for (int j = 0; j < 4; j++) {
        int idx = tid2 + 128 * j;
        int key = idx >> 4, g = idx & 15;
        *(uint4*)(&Ksp[key * 128 + ((g ^ (key & 7)) * 8)]) = kst[j];
        int c = idx >> 2, gm = idx & 3;
        *(uint4*)(&Vsp[c * 32 + ((gm ^ (c & 3)) * 8)]) = vst[j];
    }
    __syncthreads();

    int buf = 0;
    for (int t = 0; t < 64; t++) {
        const bool more = (t + 1 < 64);
        if (more) {
            const int m0n = kbase + (t + 1) * 32;
#pragma unroll
            for (int j = 0; j < 4; j++) {
                int idx = tid2 + 128 * j;
                int key = idx >> 4, g = idx & 15;
                kst[j] = *(const uint4*)(Kb + (size_t)(m0n + key) * NCH + g * 8);
                int c = idx >> 2, gm = idx & 3;
                vst[j] = *(const uint4*)(Vb + (size_t)c * NN3 + m0n + gm * 8);
            }
        }
        // ---- QK^T (swapped): sacc[key-rows][q-cols] ----
        f32x16 sacc;
#pragma unroll
        for (int r = 0; r < 16; r++) sacc[r] = 0.f;
        __builtin_amdgcn_s_setprio(1);
#pragma unroll
        for (int dc = 0; dc < 8; dc++) {
            FragU bq; bq.q = qf[dc];
            FragU ak;
            ak.q = *(const uint4*)(&Ksp[buf * 4096 + i31 * 128 + (((2 * dc + h) ^ (i31 & 7)) * 8)]);
            sacc = __builtin_amdgcn_mfma_f32_32x32x16_bf16(ak.v, bq.v, sacc, 0, 0, 0);
        }
        __builtin_amdgcn_s_setprio(0);
        // ---- online softmax (lane q = i31) ----
        float tmax = -3.0e38f;
#pragma unroll
        for (int r = 0; r < 16; r++) tmax = fmaxf(tmax, sacc[r]);
        tmax = fmaxf(tmax, __shfl_xor(tmax, 32, 64));
        if (__any(tmax > m_run)) {
            float newm = fmaxf(m_run, tmax);
            float scale = __expf(m_run - newm);
            m_run = newm;
            l_run *= scale;
#pragma unroll
            for (int reg = 0; reg < 16; reg++) {
                int qrow = (reg & 3) + 8 * (reg >> 2) + 4 * h;
                float sc = __shfl(scale, qrow, 64);
#pragma unroll
                for (int cf = 0; cf < 4; cf++) o[cf][reg] *= sc;
            }
        }
        float psum = 0.f;
#pragma unroll
        for (int r = 0; r < 16; r++) {
            float e = __expf(sacc[r] - m_run);
            sacc[r] = e;
            psum += e;
        }
        psum += __shfl_xor(psum, 32, 64);
        l_run += psum;
        uint32_t pk[8];
#pragma unroll
        for (int j = 0; j < 8; j++) pk[j] = pkbf(sacc[2 * j], sacc[2 * j + 1]);
        // ---- PV ----
        __builtin_amdgcn_s_setprio(1);
#pragma unroll
        for (int kc = 0; kc < 2; kc++) {
            uint32_t own_lo  = pk[4 * kc + 0];
            uint32_t own_lo2 = pk[4 * kc + 1];
            uint32_t own_hi  = pk[4 * kc + 2];
            uint32_t own_hi2 = pk[4 * kc + 3];
            uint32_t send1 = h ? own_lo  : own_hi;
            uint32_t send2 = h ? own_lo2 : own_hi2;
            uint32_t recv1 = (uint32_t)__shfl_xor((int)send1, 32, 64);
            uint32_t recv2 = (uint32_t)__shfl_xor((int)send2, 32, 64);
            FragU pa;
            pa.u[0] = h ? recv1 : own_lo;
            pa.u[1] = h ? recv2 : own_lo2;
            pa.u[2] = h ? own_hi  : recv1;
            pa.u[3] = h ? own_hi2 : recv2;
#pragma unroll
            for (int cf = 0; cf < 4; cf++) {
                FragU vbf;
                vbf.q = *(const uint4*)(&Vsp[buf * 4096 + (cf * 32 + i31) * 32 + (((2 * kc + h) ^ (i31 & 3)) * 8)]);
                o[cf] = __builtin_amdgcn_mfma_f32_32x32x16_bf16(pa.v, vbf.v, o[cf], 0, 0, 0);
            }
        }
        __builtin_amdgcn_s_setprio(0);
        if (more) {
#pragma unroll
            for (int j = 0; j < 4; j++) {
                int idx = tid2 + 128 * j;
                int key = idx >> 4, g = idx & 15;
                *(uint4*)(&Ksp[(buf ^ 1) * 4096 + key * 128 + ((g ^ (key & 7)) * 8)]) = kst[j];
                int c = idx >> 2, gm = idx & 3;
                *(uint4*)(&Vsp[(buf ^ 1) * 4096 + c * 32 + ((gm ^ (c & 3)) * 8)]) = vst[j];
            }
        }
        __syncthreads();
        buf ^= 1;
    }
    // ---- merge key-halves through LDS ----
    float* mo = (float*)smem;                 // [2][32][132] + ml[128]
    const int s = wid & 1;
    if (wid >= 2) {
        float* mos = mo + s * 4224;
#pragma unroll
        for (int cf = 0; cf < 4; cf++)
#pragma unroll
            for (int reg = 0; reg < 16; reg++) {
                int qrow = (reg & 3) + 8 * (reg >> 2) + 4 * h;
                mos[qrow * 132 + cf * 32 + i31] = o[cf][reg];
            }
        float* ml = mo + 8448;
        if (h == 0) { ml[s * 64 + i31] = m_run; ml[s * 64 + 32 + i31] = l_run; }
    }
    __syncthreads();
    if (wid < 2) {
        float* mos = mo + s * 4224;
        float* ml  = mo + 8448;
        float m2 = ml[s * 64 + i31];
        float l2 = ml[s * 64 + 32 + i31];
        float M  = fmaxf(m_run, m2);
        float a0 = __expf(m_run - M);
        float a2 = __expf(m2 - M);
        float inv = 1.0f / (a0 * l_run + a2 * l2);
#pragma unroll
        for (int reg = 0; reg < 16; reg++) {
            int qrow = (reg & 3) + 8 * (reg >> 2) + 4 * h;
            float a0q = __shfl(a0, qrow, 64);
            float a2q = __shfl(a2, qrow, 64);
            float ivq = __shfl(inv, qrow, 64);
            unsigned short* row = AO + ((size_t)b * NN2 + q0w + qrow) * NCH;
#pragma unroll
            for (int cf = 0; cf < 4; cf++) {
                float val = (a0q * o[cf][reg] + a2q * mos[qrow * 132 + cf * 32 + i31]) * ivq;
                row[cf * 32 + i31] = f2bf(val);
            }
        }
    }
}

// ---------------------------------------------------------------------------
// Kernel 4: outproj -> X in bf16 NHWC (unchanged from round 7, incl. fix)
// ---------------------------------------------------------------------------
__global__ __launch_bounds__(256) void outproj(const unsigned short* __restrict__ AO,
                                               const float* __restrict__ Wo,
                                               const float* __restrict__ bo,
                                               const float* __restrict__ f2d,
                                               unsigned short* __restrict__ Xn) {
    __shared__ __align__(16) float smem[2176 + 4224];
    float* Wt = smem;
    float* At = smem + 2176;
    const int tid = threadIdx.x;
    const int b = blockIdx.x >> 7;
    const int r = blockIdx.x & 127;
    const int co0 = (r >> 5) << 6;
    const int n0  = (r & 31) << 7;
    const int tx = tid & 15, ty = tid >> 4;
    float acc[4][2][4];
#pragma unroll
    for (int i = 0; i < 4; i++)
#pragma unroll
        for (int v = 0; v < 2; v++)
#pragma unroll
            for (int u = 0; u < 4; u++) acc[i][v][u] = 0.f;
    for (int c0 = 0; c0 < NCH; c0 += 32) {
#pragma unroll
        for (int i = 0; i < 2; i++) {
            int cidx = tid + 256 * i;
            int cr = cidx >> 3, koff = (cidx & 7) << 2;
            f4 w = *(const f4*)(Wo + (co0 + cr) * NCH + c0 + koff);
            Wt[(koff + 0) * 68 + cr] = w.x;
            Wt[(koff + 1) * 68 + cr] = w.y;
            Wt[(koff + 2) * 68 + cr] = w.z;
            Wt[(koff + 3) * 68 + cr] = w.w;
        }
#pragma unroll
        for (int i = 0; i < 4; i++) {
            int cidx = tid + 256 * i;
            int nn = cidx >> 3, koff = (cidx & 7) << 2;
            ushort4 a4 = *(const ushort4*)(AO + ((size_t)b * NN2 + n0 + nn) * NCH + c0 + koff);
            At[(koff + 0) * 132 + nn] = bf2f(a4.x);
            At[(koff + 1) * 132 + nn] = bf2f(a4.y);
            At[(koff + 2) * 132 + nn] = bf2f(a4.z);
            At[(koff + 3) * 132 + nn] = bf2f(a4.w);
        }
        __syncthreads();
#pragma unroll 8
        for (int kk = 0; kk < 32; kk++) {
            f4 a4 = *(const f4*)(Wt + kk * 68 + 4 * ty);
            f4 x0 = *(const f4*)(At + kk * 132 + 4 * tx);
            f4 x1 = *(const f4*)(At + kk * 132 + 4 * tx + 64);
            float av[4] = {a4.x, a4.y, a4.z, a4.w};
#pragma unroll
            for (int i = 0; i < 4; i++) { fma4(acc[i][0], av[i], x0); fma4(acc[i][1], av[i], x1); }
        }
        __syncthreads();
    }
    unsigned short* tb = (unsigned short*)smem;
#pragma unroll
    for (int i = 0; i < 4; i++) {
        int co = co0 + 4 * ty + i;
        float bias = bo[co];
        const size_t rowb = ((size_t)b * C2 + co) * NN2 + n0;
#pragma unroll
        for (int v = 0; v < 2; v++) {
            size_t pidx = rowb + 4 * tx + 64 * v;
            f4 f = *(const f4*)(f2d + pidx);
            int nl = 4 * tx + 64 * v;
            tb[(nl + 0) * 72 + 4 * ty + i] = f2bf(acc[i][v][0] + bias + f.x);
            tb[(nl + 1) * 72 + 4 * ty + i] = f2bf(acc[i][v][1] + bias + f.y);
            tb[(nl + 2) * 72 + 4 * ty + i] = f2bf(acc[i][v][2] + bias + f.z);
            tb[(nl + 3) * 72 + 4 * ty + i] = f2bf(acc[i][v][3] + bias + f.w);
        }
    }
    __syncthreads();
#pragma unroll
    for (int k = 0; k < 4; k++) {
        int unit = tid + 256 * k;               // 1024 units of 16B
        int nl = unit >> 3, cc = unit & 7;
        uint4 d = *(const uint4*)(tb + nl * 72 + cc * 8);
        *(uint4*)(Xn + ((size_t)b * NN2 + n0 + nl) * C2 + co0 + cc * 8) = d;
    }
}

// ---------------------------------------------------------------------------
// Kernel 5: 3x3 conv via bf16 MFMA implicit GEMM (unchanged from round 7)
// ---------------------------------------------------------------------------
__global__ __launch_bounds__(256) void conv3x3(const unsigned short* __restrict__ Xn,
                                               const unsigned short* __restrict__ Wb,
                                               const float* __restrict__ bps,
                                               float* __restrict__ Y) {
    __shared__ __align__(16) unsigned short Xs[680 * 8];
    const int tid = threadIdx.x;
    const int b  = blockIdx.x >> 6;
    const int r  = blockIdx.x & 63;
    const int ct = r >> 4;
    const int pt = r & 15;
    const int px0 = (pt & 1) << 5;
    const int py0 = (pt >> 1) << 3;
    const int w    = tid >> 6;
    const int lane = tid & 63;
    const int i31  = lane & 31;
    const int h    = lane >> 5;
    const int co0  = ct << 6;

    f32x16 acc[2][2];
#pragma unroll
    for (int ch = 0; ch < 2; ch++)
#pragma unroll
        for (int pf = 0; pf < 2; pf++)
#pragma unroll
            for (int q = 0; q < 16; q++) acc[ch][pf][q] = 0.f;

    const unsigned short* Xb = Xn + (size_t)b * NN2 * C2;

    uint4 sreg[3];
    int su[3], sy[3], sx[3], sh[3];
#pragma unroll
    for (int k = 0; k < 3; k++) {
        int u = tid + 256 * k;
        su[k] = (u < 680);
        int pix = u >> 1;
        sy[k] = pix / 34;
        sx[k] = pix - sy[k] * 34;
        sh[k] = u & 1;
    }

    auto stage_load = [&](int ci0) {
#pragma unroll
        for (int k = 0; k < 3; k++) {
            uint4 z = {0, 0, 0, 0};
            if (su[k]) {
                int gy = py0 - 1 + sy[k];
                int gx = px0 - 1 + sx[k];
                if ((unsigned)gy < 64u && (unsigned)gx < 64u)
                    z = *(const uint4*)(Xb + ((size_t)(gy * 64 + gx)) * C2 + ci0 + 8 * sh[k]);
            }
            sreg[k] = z;
        }
    };
    auto stage_write = [&]() {
#pragma unroll
        for (int k = 0; k < 3; k++) {
            if (su[k]) {
                int slot = (sy[k] * 2 + sh[k]) * 34 + sx[k];
                *(uint4*)(&Xs[slot * 8]) = sreg[k];
            }
        }
    };

    stage_load(0);
    stage_write();
    __syncthreads();

    for (int c = 0; c < 16; c++) {
        if (c + 1 < 16) stage_load((c + 1) * 16);
        const int ci0 = c * 16;
#pragma unroll
        for (int t = 0; t < 9; t++) {
            const int dy = t / 3, dx = t - dy * 3;
            FragU a0, a1;
            a0.q = *(const uint4*)(Wb + ((size_t)(t * 256 + co0 + i31)) * 256 + ci0 + 8 * h);
            a1.q = *(const uint4*)(Wb + ((size_t)(t * 256 + co0 + 32 + i31)) * 256 + ci0 + 8 * h);
#pragma unroll
            for (int pf = 0; pf < 2; pf++) {
                const int yl = 2 * w + pf;
                FragU bx;
                bx.q = *(const uint4*)(&Xs[(((yl + dy) * 2 + h) * 34 + i31 + dx) * 8]);
                acc[0][pf] = __builtin_amdgcn_mfma_f32_32x32x16_bf16(a0.v, bx.v, acc[0][pf], 0, 0, 0);
                acc[1][pf] = __builtin_amdgcn_mfma_f32_32x32x16_bf16(a1.v, bx.v, acc[1][pf], 0, 0, 0);
            }
        }
        __syncthreads();
        if (c + 1 < 16) stage_write();
        __syncthreads();
    }

#pragma unroll
    for (int ch = 0; ch < 2; ch++)
#pragma unroll
        for (int pf = 0; pf < 2; pf++) {
            const int y = py0 + 2 * w + pf;
            const int x = px0 + i31;
#pragma unroll
            for (int q = 0; q < 16; q++) {
                int co = co0 + ch * 32 + (q & 3) + 8 * (q >> 2) + 4 * h;
                Y[(((size_t)b * C2 + co) * 64 + y) * 64 + x] = acc[ch][pf][q] + bps[co];
            }
        }
}

// ---------------------------------------------------------------------------
// Workspace (ushort elems):
//  Qb 0 | Kb 4194304 | Vtb 8388608 | AOb 12582912 | Xnb 16777216
//  Wbb 25165824 (+589824) | Wqb 25755648 (+32768) | Wkb 25788416 (+65536)
//  Wvb 25853952 (+65536) -> end 25919488 shorts ≈ 51.8 MiB
// ---------------------------------------------------------------------------
extern "C" void kernel_launch(void* const* d_in, const int* in_sizes, int n_in,
                              void* d_out, int out_size, void* d_ws, size_t ws_size,
                              hipStream_t stream) {
    const float* f2d = (const float*)d_in[0];
    const float* f3d = (const float*)d_in[1];
    const float* Wq  = (const float*)d_in[2];
    const float* bq  = (const float*)d_in[3];
    const float* Wk  = (const float*)d_in[4];
    const float* bk  = (const float*)d_in[5];
    const float* Wv  = (const float*)d_in[6];
    const float* bv  = (const float*)d_in[7];
    const float* Wo  = (const float*)d_in[8];
    const float* bo  = (const float*)d_in[9];
    const float* Wps = (const float*)d_in[10];
    const float* bps = (const float*)d_in[11];
    float* Y = (float*)d_out;

    unsigned short* Qb  = (unsigned short*)d_ws;
    unsigned short* Kb  = Qb + 4194304;
    unsigned short* Vtb = Kb + 4194304;
    unsigned short* AOb = Vtb + 4194304;
    unsigned short* Xnb = AOb + 4194304;
    unsigned short* Wbb = Xnb + 8388608;
    unsigned short* Wqb = Wbb + 589824;
    unsigned short* Wkb = Wqb + 32768;
    unsigned short* Wvb = Wkb + 65536;

    dim3 blk(256);
    wprep   <<<dim3(2304), blk, 0, stream>>>(Wps, Wbb);
    wprep2  <<<dim3(640),  blk, 0, stream>>>(Wq, Wk, Wv, Wqb, Wkb, Wvb);
    proj_q  <<<dim3(256),  blk, 0, stream>>>(f2d, Wqb, bq, Qb);
    proj_kv <<<dim3(256),  blk, 0, stream>>>(f3d, Wkb, bk, Wvb, bv, Kb, Vtb);
    attn    <<<dim3(512),  blk, 0, stream>>>(Qb, Kb, Vtb, AOb);
    outproj <<<dim3(1024), blk, 0, stream>>>(AOb, Wo, bo, f2d, Xnb);
    conv3x3 <<<dim3(512),  blk, 0, stream>>>(Xnb, Wbb, bps, Y);
}